// Round 7
// baseline (253.844 us; speedup 1.0000x reference)
//
#include <hip/hip_runtime.h>
#include <math.h>

#define NB    4
#define NCLS  5
#define NSHOT 5
#define NQ    75
#define CH    640
#define HW    100
#define SLICE (CH*HW)          // 64000
#define TEMP_INV 4.0f
#define EPSN  1e-12f

typedef float f32x4 __attribute__((ext_vector_type(4)));

// workspace float offsets
#define OFF_PROTO 0            // 1,280,000
#define OFF_PINV  1280000      // 2,000
#define OFF_PBAR  1282000      // 12,800
#define OFF_QINV  1294800      // 30,000
#define OFF_QBAR  1324800      // 192,000

// K1: proto[bn, cc, i] = mean over K shots of fspt
__global__ void k_proto(const float* __restrict__ fspt, float* __restrict__ proto) {
    int v = blockIdx.x * 256 + threadIdx.x;      // float4 index, 320000 total
    if (v >= (NB*NCLS*SLICE)/4) return;
    int p  = v * 4;
    int bn = p / SLICE;
    size_t base = (size_t)bn * NSHOT * SLICE + (p - bn * SLICE);
    f32x4 a = *reinterpret_cast<const f32x4*>(fspt + base);
    for (int k = 1; k < NSHOT; k++)
        a += *reinterpret_cast<const f32x4*>(fspt + base + (size_t)k * SLICE);
    a *= 0.2f;
    *reinterpret_cast<f32x4*>(proto + p) = a;
}

// K2: per-slice stats for proto (blk<20) and fqry (blk>=20).
__global__ void k_stats(const float* __restrict__ proto, const float* __restrict__ fqry,
                        float* __restrict__ pinv, float* __restrict__ pbar,
                        float* __restrict__ qinv, float* __restrict__ qbar) {
    __shared__ float inv_s[HW];
    __shared__ float part_s[256];
    int blk = blockIdx.x;
    bool isP = blk < NB * NCLS;
    int s = isP ? blk : blk - NB * NCLS;
    const float* base = (isP ? proto : fqry) + (size_t)s * SLICE;
    float* inv = (isP ? pinv : qinv) + s * HW;
    float* bar = (isP ? pbar : qbar) + s * CH;
    int t = threadIdx.x;

    float partial = 0.f;
    if (t < 200) {
        int i  = (t < 100) ? t : t - 100;
        int c0 = (t < 100) ? 0 : CH / 2;
        const float* p = base + (size_t)c0 * HW + i;
        #pragma unroll 8
        for (int cc = 0; cc < CH / 2; cc++) { float x = p[cc * HW]; partial += x * x; }
    }
    part_s[t] = partial;
    __syncthreads();
    if (t < HW) {
        float iv = 1.0f / fmaxf(sqrtf(part_s[t] + part_s[t + 100]), EPSN);
        inv_s[t] = iv;
        inv[t] = iv;
    }
    __syncthreads();
    for (int cc = t; cc < CH; cc += 256) {
        float acc = 0.f;
        const f32x4* r = reinterpret_cast<const f32x4*>(base + (size_t)cc * HW);
        #pragma unroll
        for (int i4 = 0; i4 < HW / 4; i4++) {
            f32x4 x = r[i4];
            acc += x.x * inv_s[i4*4] + x.y * inv_s[i4*4+1] + x.z * inv_s[i4*4+2] + x.w * inv_s[i4*4+3];
        }
        bar[cc] = acc * (1.0f / HW);
    }
}

// K3: fused attention + output writer. 256 threads.
// blk < 500:  ap panel (bn, qg): 3 q's -> compute ap rows, write 3 out0 slices.
// blk >= 500: aq panel (bq, ng): 3 or 2 n's -> compute aq rows, write out1 slices.
__global__ void k_att_out(const float* __restrict__ proto, const float* __restrict__ fqry,
                          const float* __restrict__ pinv, const float* __restrict__ pbar,
                          const float* __restrict__ qinv, const float* __restrict__ qbar,
                          float* __restrict__ out) {
    __shared__ __align__(16) float smem[2920];   // 11.7 KB
    float* vec_s  = smem;            // up to 3*CH = 1920
    float* part_s = smem + 1920;     // 3*200 = 600
    float* inv_s  = smem + 2520;     // 100
    float* att_s  = smem + 2620;     // 3*100 = 300
    const size_t OUT1 = (size_t)NB * NQ * NCLS * SLICE;
    int blk = blockIdx.x;
    int t = threadIdx.x;
    int w = t >> 6, l = t & 63;

    // -------- resolve panel --------
    bool isAp = blk < NB * NCLS * 25;
    int cnt, bn, bq, n0, qbase_row;
    const float* slice_src;
    if (isAp) {
        bn = blk / 25;
        int qg = blk - bn * 25;               // 25 groups of 3 q
        int b = bn / NCLS;
        cnt = 3;
        qbase_row = b * NQ + qg * 3;          // first q row
        n0 = bn - b * NCLS;                   // class n
        bq = -1;
        slice_src = proto + (size_t)bn * SLICE;
    } else {
        int pid = blk - NB * NCLS * 25;
        bq = pid >> 1;
        int ng = pid & 1;
        int b = bq / NQ;
        n0 = ng ? 3 : 0;
        cnt = ng ? 2 : 3;
        bn = b * NCLS + n0;                   // first pbar row
        qbase_row = -1;
        slice_src = fqry + (size_t)bq * SLICE;
    }

    // -------- stage vectors + inv --------
    {
        const float* vsrc = isAp ? (qbar + (size_t)qbase_row * CH)
                                 : (pbar + (size_t)bn * CH);
        const f32x4* v4 = reinterpret_cast<const f32x4*>(vsrc);
        f32x4* d4 = reinterpret_cast<f32x4*>(vec_s);
        int nv = cnt * CH / 4;
        for (int k = t; k < nv; k += 256) d4[k] = v4[k];
        const float* isrc = isAp ? (pinv + (isAp ? bn : 0) * HW) : (qinv + bq * HW);
        if (t < HW) inv_s[t] = isrc[t] * TEMP_INV;
    }
    __syncthreads();

    // -------- dot: 200 lanes, each one i, one c-half --------
    if (t < 200) {
        int i  = (t < 100) ? t : t - 100;
        int c0 = (t < 100) ? 0 : CH / 2;
        const float* p = slice_src + (size_t)c0 * HW + i;
        const float* v0 = vec_s + c0;
        float a0 = 0.f, a1 = 0.f, a2 = 0.f;
        for (int cc = 0; cc < CH / 2; cc++) {
            float pv = p[cc * HW];
            a0 += pv * v0[cc];
            a1 += pv * v0[CH + cc];
            a2 += pv * v0[2 * CH + cc];
        }
        part_s[t] = a0;
        part_s[200 + t] = a1;
        part_s[400 + t] = a2;
    }
    __syncthreads();

    // -------- softmax: wave w handles row w (w < cnt) --------
    if (w < cnt) {
        const float* ps = part_s + w * 200;
        float sv0 = (ps[l] + ps[l + 100]) * inv_s[l];
        float sv1 = (l < 36) ? (ps[l + 64] + ps[l + 164]) * inv_s[l + 64] : -INFINITY;
        float m = fmaxf(sv0, sv1);
        #pragma unroll
        for (int o = 32; o >= 1; o >>= 1) m = fmaxf(m, __shfl_xor(m, o, 64));
        float e0 = __expf(sv0 - m);
        float e1 = (l < 36) ? __expf(sv1 - m) : 0.f;
        float sm = e0 + e1;
        #pragma unroll
        for (int o = 32; o >= 1; o >>= 1) sm += __shfl_xor(sm, o, 64);
        float inv = 1.0f / sm;
        att_s[w * HW + l] = e0 * inv + 1.0f;
        if (l < 36) att_s[w * HW + l + 64] = e1 * inv + 1.0f;
    }
    __syncthreads();

    // -------- write phase: cnt slices, contiguous nt-store streams --------
    const f32x4* s4 = reinterpret_cast<const f32x4*>(slice_src);
    for (int j = 0; j < cnt; j++) {
        float* ob;
        if (isAp) {
            // out0[b, q, n, :, :]  with q = qbase_row + j (absolute row b*NQ+q = qbase_row+j)
            ob = out + ((size_t)(qbase_row + j) * NCLS + n0) * SLICE;
        } else {
            ob = out + OUT1 + ((size_t)bq * NCLS + (n0 + j)) * SLICE;
        }
        const float* arow = att_s + j * HW;
        for (int k = t; k < SLICE / 4; k += 256) {
            int i4 = (k * 4) % HW;            // f4-aligned within att row
            f32x4 av = *reinterpret_cast<const f32x4*>(arow + i4);
            f32x4 sv = s4[k];
            __builtin_nontemporal_store(sv * av, reinterpret_cast<f32x4*>(ob + (size_t)k * 4));
        }
    }
}

extern "C" void kernel_launch(void* const* d_in, const int* in_sizes, int n_in,
                              void* d_out, int out_size, void* d_ws, size_t ws_size,
                              hipStream_t stream) {
    const float* fspt = (const float*)d_in[0];
    const float* fqry = (const float*)d_in[1];
    float* ws  = (float*)d_ws;
    float* out = (float*)d_out;

    float* proto = ws + OFF_PROTO;
    float* pinv  = ws + OFF_PINV;
    float* pbar  = ws + OFF_PBAR;
    float* qinv  = ws + OFF_QINV;
    float* qbar  = ws + OFF_QBAR;

    k_proto<<<1250, 256, 0, stream>>>(fspt, proto);
    k_stats<<<NB * NCLS + NB * NQ, 256, 0, stream>>>(proto, fqry, pinv, pbar, qinv, qbar);
    k_att_out<<<NB * NCLS * 25 + NB * NQ * 2, 256, 0, stream>>>(proto, fqry, pinv, pbar,
                                                                qinv, qbar, out);
}

// Round 8
// 236.796 us; speedup vs baseline: 1.0720x; 1.0720x over previous
//
#include <hip/hip_runtime.h>
#include <math.h>

#define NB    4
#define NCLS  5
#define NSHOT 5
#define NQ    75
#define CH    640
#define HW    100
#define SLICE (CH*HW)          // 64000
#define TEMP_INV 4.0f
#define EPSN  1e-12f

typedef float f32x4 __attribute__((ext_vector_type(4)));

// workspace float offsets
#define OFF_PROTO 0            // 1,280,000
#define OFF_PINV  1280000      // 2,000
#define OFF_PBAR  1282000      // 12,800
#define OFF_QINV  1294800      // 30,000
#define OFF_QBAR  1324800      // 192,000
#define OFF_AP    1516800      // 150,000
#define OFF_AQ    1666800      // 150,000

// K1: proto[bn, cc, i] = mean over K shots of fspt
__global__ void k_proto(const float* __restrict__ fspt, float* __restrict__ proto) {
    int v = blockIdx.x * 256 + threadIdx.x;      // float4 index, 320000 total
    if (v >= (NB*NCLS*SLICE)/4) return;
    int p  = v * 4;
    int bn = p / SLICE;
    size_t base = (size_t)bn * NSHOT * SLICE + (p - bn * SLICE);
    f32x4 a = *reinterpret_cast<const f32x4*>(fspt + base);
    for (int k = 1; k < NSHOT; k++)
        a += *reinterpret_cast<const f32x4*>(fspt + base + (size_t)k * SLICE);
    a *= 0.2f;
    *reinterpret_cast<f32x4*>(proto + p) = a;
}

// K2: per-slice stats for proto (blk<20) and fqry (blk>=20).
__global__ void k_stats(const float* __restrict__ proto, const float* __restrict__ fqry,
                        float* __restrict__ pinv, float* __restrict__ pbar,
                        float* __restrict__ qinv, float* __restrict__ qbar) {
    __shared__ float inv_s[HW];
    __shared__ float part_s[256];
    int blk = blockIdx.x;
    bool isP = blk < NB * NCLS;
    int s = isP ? blk : blk - NB * NCLS;
    const float* base = (isP ? proto : fqry) + (size_t)s * SLICE;
    float* inv = (isP ? pinv : qinv) + s * HW;
    float* bar = (isP ? pbar : qbar) + s * CH;
    int t = threadIdx.x;

    float partial = 0.f;
    if (t < 200) {
        int i  = (t < 100) ? t : t - 100;
        int c0 = (t < 100) ? 0 : CH / 2;
        const float* p = base + (size_t)c0 * HW + i;
        #pragma unroll 8
        for (int cc = 0; cc < CH / 2; cc++) { float x = p[cc * HW]; partial += x * x; }
    }
    part_s[t] = partial;
    __syncthreads();
    if (t < HW) {
        float iv = 1.0f / fmaxf(sqrtf(part_s[t] + part_s[t + 100]), EPSN);
        inv_s[t] = iv;
        inv[t] = iv;
    }
    __syncthreads();
    for (int cc = t; cc < CH; cc += 256) {
        float acc = 0.f;
        const f32x4* r = reinterpret_cast<const f32x4*>(base + (size_t)cc * HW);
        #pragma unroll
        for (int i4 = 0; i4 < HW / 4; i4++) {
            f32x4 x = r[i4];
            acc += x.x * inv_s[i4*4] + x.y * inv_s[i4*4+1] + x.z * inv_s[i4*4+2] + x.w * inv_s[i4*4+3];
        }
        bar[cc] = acc * (1.0f / HW);
    }
}

// K3: fused attention maps (R5 form). blk<100 -> ap panel (bn,qg); blk>=100 -> aq panel (bq).
__global__ void k_att(const float* __restrict__ proto, const float* __restrict__ fqry,
                      const float* __restrict__ pinv, const float* __restrict__ pbar,
                      const float* __restrict__ qinv, const float* __restrict__ qbar,
                      float* __restrict__ ap, float* __restrict__ aq) {
    __shared__ float smem[12700];        // 50.8 KB, carved per path
    int blk = blockIdx.x;
    int t = threadIdx.x;
    int w = t >> 6, l = t & 63;

    if (blk < NB * NCLS * 5) {
        // ---- ap panel: (bn, qg), 15 q's ----
        float* qb_s   = smem;             // 15*CH = 9600
        float* part_s = smem + 9600;      // 15*200 = 3000
        float* piv_s  = smem + 12600;     // 100
        int bn = blk / 5;
        int qg = blk - bn * 5;
        int b  = bn / NCLS;

        for (int qq = 0; qq < 15; qq++) {
            int bq = b * NQ + qg * 15 + qq;
            for (int cc = t; cc < CH; cc += 256) qb_s[qq * CH + cc] = qbar[bq * CH + cc];
        }
        if (t < HW) piv_s[t] = pinv[bn * HW + t] * TEMP_INV;
        __syncthreads();

        if (t < 200) {
            int i  = (t < 100) ? t : t - 100;
            int c0 = (t < 100) ? 0 : CH / 2;
            const float* p = proto + (size_t)bn * SLICE + (size_t)c0 * HW + i;
            float acc[15];
            #pragma unroll
            for (int qq = 0; qq < 15; qq++) acc[qq] = 0.f;
            for (int cc = 0; cc < CH / 2; cc++) {
                float pv = p[cc * HW];
                #pragma unroll
                for (int qq = 0; qq < 15; qq++) acc[qq] += pv * qb_s[qq * CH + c0 + cc];
            }
            #pragma unroll
            for (int qq = 0; qq < 15; qq++) part_s[qq * 200 + t] = acc[qq];
        }
        __syncthreads();

        for (int qq = w; qq < 15; qq += 4) {
            float sv0 = (part_s[qq*200 + l] + part_s[qq*200 + l + 100]) * piv_s[l];
            float sv1 = (l < 36) ? (part_s[qq*200 + l + 64] + part_s[qq*200 + l + 164]) * piv_s[l + 64] : -INFINITY;
            float m = fmaxf(sv0, sv1);
            #pragma unroll
            for (int o = 32; o >= 1; o >>= 1) m = fmaxf(m, __shfl_xor(m, o, 64));
            float e0 = __expf(sv0 - m);
            float e1 = (l < 36) ? __expf(sv1 - m) : 0.f;
            float sm = e0 + e1;
            #pragma unroll
            for (int o = 32; o >= 1; o >>= 1) sm += __shfl_xor(sm, o, 64);
            float inv = 1.0f / sm;
            int bqn = (b * NQ + qg * 15 + qq) * NCLS + (bn - b * NCLS);
            float* dst = ap + (size_t)bqn * HW;
            dst[l] = e0 * inv + 1.0f;
            if (l < 36) dst[l + 64] = e1 * inv + 1.0f;
        }
    } else {
        // ---- aq panel: one bq, 5 n's ----
        float* pb_s   = smem;             // NCLS*CH = 3200
        float* part_s = smem + 3200;      // NCLS*200 = 1000
        float* qiv_s  = smem + 4200;      // 100
        int bq = blk - NB * NCLS * 5;
        int b  = bq / NQ;

        for (int k = t; k < NCLS * CH; k += 256) pb_s[k] = pbar[(size_t)b * NCLS * CH + k];
        if (t < HW) qiv_s[t] = qinv[bq * HW + t] * TEMP_INV;
        __syncthreads();

        if (t < 200) {
            int i  = (t < 100) ? t : t - 100;
            int c0 = (t < 100) ? 0 : CH / 2;
            const float* p = fqry + (size_t)bq * SLICE + (size_t)c0 * HW + i;
            float acc[NCLS];
            #pragma unroll
            for (int n = 0; n < NCLS; n++) acc[n] = 0.f;
            for (int cc = 0; cc < CH / 2; cc++) {
                float pv = p[cc * HW];
                #pragma unroll
                for (int n = 0; n < NCLS; n++) acc[n] += pv * pb_s[n * CH + c0 + cc];
            }
            #pragma unroll
            for (int n = 0; n < NCLS; n++) part_s[n * 200 + t] = acc[n];
        }
        __syncthreads();

        for (int n = w; n < NCLS; n += 4) {
            float sv0 = (part_s[n*200 + l] + part_s[n*200 + l + 100]) * qiv_s[l];
            float sv1 = (l < 36) ? (part_s[n*200 + l + 64] + part_s[n*200 + l + 164]) * qiv_s[l + 64] : -INFINITY;
            float m = fmaxf(sv0, sv1);
            #pragma unroll
            for (int o = 32; o >= 1; o >>= 1) m = fmaxf(m, __shfl_xor(m, o, 64));
            float e0 = __expf(sv0 - m);
            float e1 = (l < 36) ? __expf(sv1 - m) : 0.f;
            float sm = e0 + e1;
            #pragma unroll
            for (int o = 32; o >= 1; o >>= 1) sm += __shfl_xor(sm, o, 64);
            float inv = 1.0f / sm;
            int bqn = bq * NCLS + n;
            float* dst = aq + (size_t)bqn * HW;
            dst[l] = e0 * inv + 1.0f;
            if (l < 36) dst[l + 64] = e1 * inv + 1.0f;
        }
    }
}

// K4: output writer, register-held input, broadcast loop, 10 KB contiguous bursts.
// 320 threads; chunk = 2560 floats (25 chunks per slice); 2 f32x4 per thread (strided).
// blk<500: out0 (bn, ch): hold proto, loop 75 q. blk>=500: out1 (bq, ch): hold fqry, loop 5 n.
__global__ void k_outs(const float* __restrict__ proto, const float* __restrict__ fqry,
                       const float* __restrict__ ap, const float* __restrict__ aq,
                       float* __restrict__ out) {
    const size_t OUT1 = (size_t)NB * NQ * NCLS * SLICE; // 96,000,000
    int blk = blockIdx.x;
    int t = threadIdx.x;

    if (blk < NB * NCLS * 25) {
        int bn = blk / 25;
        int ch = blk - bn * 25;
        int off0 = ch * 2560 + t * 4;
        int off1 = off0 + 1280;
        int i0 = off0 % HW;
        int i1 = off1 % HW;
        int b = bn / NCLS, n = bn - b * NCLS;
        f32x4 pv0 = *reinterpret_cast<const f32x4*>(proto + (size_t)bn * SLICE + off0);
        f32x4 pv1 = *reinterpret_cast<const f32x4*>(proto + (size_t)bn * SLICE + off1);
        const float* apb = ap + (size_t)(b * NQ * NCLS + n) * HW;
        float* ob = out + (size_t)(b * NQ * NCLS + n) * SLICE;
        #pragma unroll 5
        for (int q = 0; q < NQ; q++) {
            const float* ar = apb + (size_t)q * NCLS * HW;
            f32x4 a0 = *reinterpret_cast<const f32x4*>(ar + i0);
            f32x4 a1 = *reinterpret_cast<const f32x4*>(ar + i1);
            float* o = ob + (size_t)q * NCLS * SLICE;
            __builtin_nontemporal_store(pv0 * a0, reinterpret_cast<f32x4*>(o + off0));
            __builtin_nontemporal_store(pv1 * a1, reinterpret_cast<f32x4*>(o + off1));
        }
    } else {
        int bb = blk - NB * NCLS * 25;
        int bq = bb / 25;
        int ch = bb - bq * 25;
        int off0 = ch * 2560 + t * 4;
        int off1 = off0 + 1280;
        int i0 = off0 % HW;
        int i1 = off1 % HW;
        f32x4 qv0 = *reinterpret_cast<const f32x4*>(fqry + (size_t)bq * SLICE + off0);
        f32x4 qv1 = *reinterpret_cast<const f32x4*>(fqry + (size_t)bq * SLICE + off1);
        const float* aqb = aq + (size_t)bq * NCLS * HW;
        float* ob = out + OUT1 + (size_t)bq * NCLS * SLICE;
        #pragma unroll
        for (int n = 0; n < NCLS; n++) {
            const float* ar = aqb + n * HW;
            f32x4 a0 = *reinterpret_cast<const f32x4*>(ar + i0);
            f32x4 a1 = *reinterpret_cast<const f32x4*>(ar + i1);
            float* o = ob + (size_t)n * SLICE;
            __builtin_nontemporal_store(qv0 * a0, reinterpret_cast<f32x4*>(o + off0));
            __builtin_nontemporal_store(qv1 * a1, reinterpret_cast<f32x4*>(o + off1));
        }
    }
}

extern "C" void kernel_launch(void* const* d_in, const int* in_sizes, int n_in,
                              void* d_out, int out_size, void* d_ws, size_t ws_size,
                              hipStream_t stream) {
    const float* fspt = (const float*)d_in[0];
    const float* fqry = (const float*)d_in[1];
    float* ws  = (float*)d_ws;
    float* out = (float*)d_out;

    float* proto = ws + OFF_PROTO;
    float* pinv  = ws + OFF_PINV;
    float* pbar  = ws + OFF_PBAR;
    float* qinv  = ws + OFF_QINV;
    float* qbar  = ws + OFF_QBAR;
    float* ap    = ws + OFF_AP;
    float* aq    = ws + OFF_AQ;

    k_proto<<<1250, 256, 0, stream>>>(fspt, proto);
    k_stats<<<NB * NCLS + NB * NQ, 256, 0, stream>>>(proto, fqry, pinv, pbar, qinv, qbar);
    k_att<<<NB * NCLS * 5 + NB * NQ, 256, 0, stream>>>(proto, fqry, pinv, pbar, qinv, qbar, ap, aq);
    k_outs<<<NB * NCLS * 25 + NB * NQ * 25, 320, 0, stream>>>(proto, fqry, ap, aq, out);
}